// Round 2
// baseline (32754.019 us; speedup 1.0000x reference)
//
#include <hip/hip_runtime.h>
#include <cstddef>
#include <cstdint>

// ---------------------------------------------------------------------------
// PredRNN V1 (L=4, HID=64, 32x32, B=4, T=20 -> 19 steps), fp32 direct conv.
// Round 1: fused x/h/m gate convs (1 launch, 896 blocks), mix fused into the
// layer-0 tile loader, 2-channel LDS staging (half the barriers), fast tanh.
// ---------------------------------------------------------------------------

#define BB 4          // batch
#define NLAYER 4
#define NSTEP 19      // output timesteps (t=0..18)

// workspace offsets (in floats)
constexpr size_t OFF_HS    = 0;              // [4][4][64][1024]
constexpr size_t OFF_CS    = 1048576;        // [4][4][64][1024]
constexpr size_t OFF_M     = 2097152;        // [4][64][1024]
constexpr size_t OFF_STATS = 2359296;        // 32 doubles (4 slots x 4 b x {S1,S2})
constexpr size_t OFF_XRAW  = 2359360;        // [4][448][1024]
constexpr size_t OFF_HRAW  = 4194368;        // [4][256][1024]
constexpr size_t OFF_MRAW  = 5242944;        // [4][192][1024]
constexpr size_t OFF_MEM   = 6029376;        // [4][128][1024]
constexpr size_t OFF_OPART = 6553664;        // [4][4][64][1024] (ci-chunk partials)
constexpr size_t OFF_ORAW  = 7602240;        // [4][64][1024]
constexpr size_t OFF_OXH   = 7864384;        // [4][64][1024]
constexpr size_t ZERO_N    = OFF_XRAW;       // zero hs,cs,m,stats each call

__device__ __forceinline__ float sigmoidf_(float x) {
    return 1.0f / (1.0f + __expf(-x));
}

__device__ __forceinline__ float fast_tanh(float x) {
    float ax = fabsf(x);
    float e = __expf(2.0f * ax);          // +inf for large ax is fine:
    float r = 1.0f - 2.0f / (e + 1.0f);   // 1 - 0 -> 1
    return copysignf(r, x);
}

__device__ __forceinline__ void ln_params(const double* stats, int slot, int b,
                                          float N, float& mu, float& rs) {
    double s1 = stats[slot * 8 + b * 2 + 0];
    double s2 = stats[slot * 8 + b * 2 + 1];
    double mud = s1 / (double)N;
    double var = s2 / (double)N - mud * mud;
    mu = (float)mud;
    float v = (float)var + 1e-5f;
    float r = rsqrtf(v);
    r = r * (1.5f - 0.5f * v * r * r);   // Newton refine
    rs = r;
}

// ---------------- fused x/h/m 5x5 gate convs, pad 2 ------------------------
// grid: b(4) x group(224): g<112 -> x-path cog, g<176 -> h-path, else m-path.
// 256 threads; thread = (row, col4): 4 px x 4 out-channels.
// Two input channels staged in LDS per barrier pair.
__global__ __launch_bounds__(256)
void convcell_k(const float* __restrict__ xin, int xin_bstride, int mode, int t,
                const float* __restrict__ x_patched, const float* __restrict__ mask,
                const float* __restrict__ prev_out,
                const float* __restrict__ wx, int wx_ci,
                const float* __restrict__ hin, const float* __restrict__ wh,
                const float* __restrict__ min_, const float* __restrict__ wm,
                float* __restrict__ xraw, float* __restrict__ hraw,
                float* __restrict__ mraw, double* __restrict__ stats) {
    __shared__ alignas(16) float tile[2 * 1336];
    const int tid = threadIdx.x;
    int bid = blockIdx.x;
    const int g = bid % 224;
    const int b = bid / 224;

    int cog, CI, CO, wci, slot;
    const float* in;
    const float* w;
    float* outp;
    int path;
    if (g < 112) {
        path = 0; cog = g;       CI = wx_ci; CO = 448; wci = wx_ci;
        w = wx; outp = xraw; slot = 0;
        in = xin + (size_t)b * xin_bstride;
    } else if (g < 176) {
        path = 1; cog = g - 112; CI = 64;    CO = 256; wci = 64;
        w = wh; outp = hraw; slot = 1;
        in = hin + (size_t)b * 65536;
    } else {
        path = 2; cog = g - 176; CI = 64;    CO = 192; wci = 64;
        w = wm; outp = mraw; slot = 2;
        in = min_ + (size_t)b * 65536;
    }
    const bool domix = (path == 0 && mode == 1);
    const float* xfp = nullptr;
    const float* mkp = nullptr;
    const float* xop = nullptr;
    if (domix) {
        xfp = x_patched + ((size_t)b * 20 + t) * 16384;
        mkp = mask + ((size_t)b * 18 + (t - 1)) * 1024;
        xop = prev_out + ((size_t)b * NSTEP + (t - 1)) * 16384;
    }
    const float* wp = w + (size_t)(cog * 4) * wci * 25;
    const int row = tid >> 3;
    const int col4 = (tid & 7) << 2;

    float acc[4][4] = {{0.f, 0.f, 0.f, 0.f}, {0.f, 0.f, 0.f, 0.f},
                       {0.f, 0.f, 0.f, 0.f}, {0.f, 0.f, 0.f, 0.f}};

    for (int ci = 0; ci < CI; ci += 2) {
        __syncthreads();
        #pragma unroll
        for (int i = 0; i < 11; ++i) {
            int idx = tid + i * 256;
            if (idx < 2592) {
                int half = (idx >= 1296) ? 1 : 0;
                int id2 = idx - half * 1296;
                int ty = id2 / 36;
                int tx = id2 - ty * 36;
                int y = ty - 2, x = tx - 2;
                float v = 0.f;
                if ((unsigned)y < 32u && (unsigned)x < 32u) {
                    int px = y * 32 + x;
                    int c = ci + half;
                    if (domix) {
                        float mk = mkp[px];
                        v = mk * xfp[c * 1024 + px] + (1.f - mk) * xop[c * 1024 + px];
                    } else {
                        v = in[c * 1024 + px];
                    }
                }
                tile[half * 1336 + ty * 37 + tx] = v;
            }
        }
        __syncthreads();
        #pragma unroll
        for (int half = 0; half < 2; ++half) {
            const float* tl = tile + half * 1336;
            const float* wpc = wp + (size_t)(ci + half) * 25;
            #pragma unroll
            for (int ky = 0; ky < 5; ++ky) {
                float win[8];
                #pragma unroll
                for (int j = 0; j < 8; ++j) win[j] = tl[(row + ky) * 37 + col4 + j];
                #pragma unroll
                for (int kx = 0; kx < 5; ++kx) {
                    #pragma unroll
                    for (int cc = 0; cc < 4; ++cc) {
                        float wv = wpc[(size_t)cc * wci * 25 + ky * 5 + kx];
                        #pragma unroll
                        for (int px = 0; px < 4; ++px)
                            acc[cc][px] = fmaf(win[kx + px], wv, acc[cc][px]);
                    }
                }
            }
        }
    }

    size_t ob = ((size_t)b * CO + cog * 4) * 1024 + row * 32 + col4;
    #pragma unroll
    for (int cc = 0; cc < 4; ++cc) {
        float4 v = make_float4(acc[cc][0], acc[cc][1], acc[cc][2], acc[cc][3]);
        *reinterpret_cast<float4*>(outp + ob + cc * 1024) = v;
    }

    // LN stats for this block's 16 outputs (slot = path)
    double s1 = 0.0, s2 = 0.0;
    #pragma unroll
    for (int cc = 0; cc < 4; ++cc)
        #pragma unroll
        for (int px = 0; px < 4; ++px) {
            double v = (double)acc[cc][px];
            s1 += v; s2 += v * v;
        }
    __syncthreads();
    double* red = reinterpret_cast<double*>(tile);
    red[tid] = s1; red[256 + tid] = s2;
    __syncthreads();
    for (int s = 128; s > 0; s >>= 1) {
        if (tid < s) { red[tid] += red[tid + s]; red[256 + tid] += red[256 + tid + s]; }
        __syncthreads();
    }
    if (tid == 0) {
        atomicAdd(&stats[slot * 8 + b * 2 + 0], red[0]);
        atomicAdd(&stats[slot * 8 + b * 2 + 1], red[256]);
    }
}

// --------------------- conv-o on mem (5x5, CI=128 in 4 chunks) -------------
__global__ __launch_bounds__(256)
void convo_k(const float* __restrict__ mem, const float* __restrict__ w,
             float* __restrict__ opart) {
    __shared__ alignas(16) float tile[2 * 1336];
    const int tid = threadIdx.x;
    int bid = blockIdx.x;              // b(4) x cog(16) x chunk(4) = 256
    const int chunk = bid & 3;
    const int cog = (bid >> 2) & 15;
    const int b = bid >> 6;
    const int ci0 = chunk * 32;

    const float* src0 = mem + (size_t)b * 131072 + (size_t)ci0 * 1024;
    const float* wp = w + ((size_t)(cog * 4) * 128 + ci0) * 25;
    const int row = tid >> 3;
    const int col4 = (tid & 7) << 2;

    float acc[4][4] = {{0.f, 0.f, 0.f, 0.f}, {0.f, 0.f, 0.f, 0.f},
                       {0.f, 0.f, 0.f, 0.f}, {0.f, 0.f, 0.f, 0.f}};

    for (int ci = 0; ci < 32; ci += 2) {
        __syncthreads();
        #pragma unroll
        for (int i = 0; i < 11; ++i) {
            int idx = tid + i * 256;
            if (idx < 2592) {
                int half = (idx >= 1296) ? 1 : 0;
                int id2 = idx - half * 1296;
                int ty = id2 / 36;
                int tx = id2 - ty * 36;
                int y = ty - 2, x = tx - 2;
                float v = 0.f;
                if ((unsigned)y < 32u && (unsigned)x < 32u)
                    v = src0[(ci + half) * 1024 + y * 32 + x];
                tile[half * 1336 + ty * 37 + tx] = v;
            }
        }
        __syncthreads();
        #pragma unroll
        for (int half = 0; half < 2; ++half) {
            const float* tl = tile + half * 1336;
            const float* wpc = wp + (size_t)(ci + half) * 25;
            #pragma unroll
            for (int ky = 0; ky < 5; ++ky) {
                float win[8];
                #pragma unroll
                for (int j = 0; j < 8; ++j) win[j] = tl[(row + ky) * 37 + col4 + j];
                #pragma unroll
                for (int kx = 0; kx < 5; ++kx) {
                    #pragma unroll
                    for (int cc = 0; cc < 4; ++cc) {
                        float wv = wpc[(size_t)cc * 128 * 25 + ky * 5 + kx];
                        #pragma unroll
                        for (int px = 0; px < 4; ++px)
                            acc[cc][px] = fmaf(win[kx + px], wv, acc[cc][px]);
                    }
                }
            }
        }
    }

    size_t ob = (size_t)chunk * 262144 + ((size_t)b * 64 + cog * 4) * 1024 + row * 32 + col4;
    #pragma unroll
    for (int cc = 0; cc < 4; ++cc) {
        float4 v = make_float4(acc[cc][0], acc[cc][1], acc[cc][2], acc[cc][3]);
        *reinterpret_cast<float4*>(opart + ob + cc * 1024) = v;
    }
}

// ------------------------------- gates -------------------------------------
#define LD4(dst, p) { float4 _v = *reinterpret_cast<const float4*>(p); \
                      (dst)[0]=_v.x; (dst)[1]=_v.y; (dst)[2]=_v.z; (dst)[3]=_v.w; }
#define ST4(p, src) { *reinterpret_cast<float4*>(p) = \
                      make_float4((src)[0], (src)[1], (src)[2], (src)[3]); }

__global__ __launch_bounds__(256)
void gates_k(const float* __restrict__ xraw, const float* __restrict__ hraw,
             const float* __restrict__ mraw, double* __restrict__ stats,
             float* __restrict__ cs_l, float* __restrict__ m_buf,
             float* __restrict__ mem, float* __restrict__ oxh) {
    int e4 = blockIdx.x * 256 + threadIdx.x;   // 65536 groups of 4 floats
    if (e4 < 8) stats[24 + e4] = 0.0;          // zero slot 3 for this cell's conv-o
    int b = e4 >> 14;
    int r = (e4 & 16383) << 2;

    float mu_x, rs_x, mu_h, rs_h, mu_m, rs_m;
    ln_params(stats, 0, b, 458752.f, mu_x, rs_x);
    ln_params(stats, 1, b, 262144.f, mu_h, rs_h);
    ln_params(stats, 2, b, 196608.f, mu_m, rs_m);

    const float* xb = xraw + (size_t)b * 458752 + r;
    const float* hb = hraw + (size_t)b * 262144 + r;
    const float* mb = mraw + (size_t)b * 196608 + r;
    float* csb  = cs_l  + (size_t)b * 65536 + r;
    float* mbb  = m_buf + (size_t)b * 65536 + r;
    float* memc = mem   + (size_t)b * 131072 + r;
    float* memm = memc + 65536;
    float* oxb  = oxh   + (size_t)b * 65536 + r;

    float X[7][4], H[4][4], M[3][4], C[4], MM[4];
    #pragma unroll
    for (int k = 0; k < 7; ++k) LD4(X[k], xb + k * 65536);
    #pragma unroll
    for (int k = 0; k < 4; ++k) LD4(H[k], hb + k * 65536);
    #pragma unroll
    for (int k = 0; k < 3; ++k) LD4(M[k], mb + k * 65536);
    LD4(C, csb);
    LD4(MM, mbb);

    float cn[4], mn[4], ox4[4];
    #pragma unroll
    for (int j = 0; j < 4; ++j) {
        float ix  = (X[0][j] - mu_x) * rs_x;
        float fx  = (X[1][j] - mu_x) * rs_x;
        float gx  = (X[2][j] - mu_x) * rs_x;
        float ixp = (X[3][j] - mu_x) * rs_x;
        float fxp = (X[4][j] - mu_x) * rs_x;
        float gxp = (X[5][j] - mu_x) * rs_x;
        float ox  = (X[6][j] - mu_x) * rs_x;
        float ih  = (H[0][j] - mu_h) * rs_h;
        float fh  = (H[1][j] - mu_h) * rs_h;
        float gh  = (H[2][j] - mu_h) * rs_h;
        float oh  = (H[3][j] - mu_h) * rs_h;
        float im  = (M[0][j] - mu_m) * rs_m;
        float fm  = (M[1][j] - mu_m) * rs_m;
        float gm  = (M[2][j] - mu_m) * rs_m;

        float i  = sigmoidf_(ix + ih);
        float f  = sigmoidf_(fx + fh + 1.0f);
        float gg = fast_tanh(gx + gh);
        float c  = f * C[j] + i * gg;
        float ip = sigmoidf_(ixp + im);
        float fp = sigmoidf_(fxp + fm + 1.0f);
        float gp = fast_tanh(gxp + gm);
        float m2 = fp * MM[j] + ip * gp;
        cn[j] = c; mn[j] = m2; ox4[j] = ox + oh;
    }
    ST4(csb, cn); ST4(mbb, mn); ST4(memc, cn); ST4(memm, mn); ST4(oxb, ox4);
}

// ------------------ sum conv-o partials + stats -----------------------------
__global__ __launch_bounds__(256)
void statso_k(const float* __restrict__ opart, float* __restrict__ oraw,
              double* __restrict__ stats) {
    __shared__ double red[512];
    int e4 = blockIdx.x * 256 + threadIdx.x;  // 65536
    int b = e4 >> 14;
    int r = e4 << 2;
    float4 v0 = *reinterpret_cast<const float4*>(opart + r);
    float4 v1 = *reinterpret_cast<const float4*>(opart + 262144 + r);
    float4 v2 = *reinterpret_cast<const float4*>(opart + 524288 + r);
    float4 v3 = *reinterpret_cast<const float4*>(opart + 786432 + r);
    float4 s;
    s.x = v0.x + v1.x + v2.x + v3.x;
    s.y = v0.y + v1.y + v2.y + v3.y;
    s.z = v0.z + v1.z + v2.z + v3.z;
    s.w = v0.w + v1.w + v2.w + v3.w;
    *reinterpret_cast<float4*>(oraw + r) = s;
    double s1 = (double)s.x + (double)s.y + (double)s.z + (double)s.w;
    double s2 = (double)s.x * s.x + (double)s.y * s.y +
                (double)s.z * s.z + (double)s.w * s.w;
    int t = threadIdx.x;
    red[t] = s1; red[256 + t] = s2;
    __syncthreads();
    for (int st = 128; st > 0; st >>= 1) {
        if (t < st) { red[t] += red[t + st]; red[256 + t] += red[256 + t + st]; }
        __syncthreads();
    }
    if (t == 0) {
        atomicAdd(&stats[24 + b * 2 + 0], red[0]);
        atomicAdd(&stats[24 + b * 2 + 1], red[256]);
    }
}

// --------------- o-gate + 1x1 conv_last + h_new -----------------------------
__global__ __launch_bounds__(256)
void final_k(const float* __restrict__ mem, const float* __restrict__ oraw,
             const float* __restrict__ oxh, double* __restrict__ stats,
             const float* __restrict__ Wl_l, float* __restrict__ hs_l) {
    int bi = blockIdx.x;              // 64 = b(4) x pxq(4) x coq(4)
    int b = bi >> 4, pxq = (bi >> 2) & 3, coq = bi & 3;
    int px = pxq * 256 + threadIdx.x;
    const float* memb = mem + (size_t)b * 131072 + px;
    float acc[16];
    #pragma unroll
    for (int k = 0; k < 16; ++k) acc[k] = 0.f;
    for (int ci = 0; ci < 128; ++ci) {
        float v = memb[ci * 1024];
        #pragma unroll
        for (int k = 0; k < 16; ++k)
            acc[k] = fmaf(v, Wl_l[(coq * 16 + k) * 128 + ci], acc[k]);
    }
    float mu, rs;
    ln_params(stats, 3, b, 65536.f, mu, rs);
    #pragma unroll
    for (int k = 0; k < 16; ++k) {
        int co = coq * 16 + k;
        size_t idx = ((size_t)b * 64 + co) * 1024 + px;
        float o = sigmoidf_(oxh[idx] + (oraw[idx] - mu) * rs);
        hs_l[idx] = o * fast_tanh(acc[k]);
    }
    if (bi == 0 && threadIdx.x < 24) stats[threadIdx.x] = 0.0;  // zero slots 0-2
}

// --------------------- 1x1 output conv (64 -> 16) ---------------------------
__global__ __launch_bounds__(256)
void out_k(const float* __restrict__ h3, const float* __restrict__ Wout,
           float* __restrict__ out, int t) {
    int e = blockIdx.x * 256 + threadIdx.x;  // 4096
    int b = e >> 10, px = e & 1023;
    const float* hb = h3 + (size_t)b * 65536 + px;
    float acc[16];
    #pragma unroll
    for (int k = 0; k < 16; ++k) acc[k] = 0.f;
    for (int ci = 0; ci < 64; ++ci) {
        float v = hb[ci * 1024];
        #pragma unroll
        for (int k = 0; k < 16; ++k) acc[k] = fmaf(v, Wout[k * 64 + ci], acc[k]);
    }
    #pragma unroll
    for (int k = 0; k < 16; ++k)
        out[(((size_t)b * NSTEP + t) * 16 + k) * 1024 + px] = acc[k];
}

// ------------------------------ init (zero state) ---------------------------
__global__ __launch_bounds__(256)
void init_k(float* __restrict__ ws) {
    size_t i = ((size_t)blockIdx.x * 256 + threadIdx.x) * 4;
    for (; i < ZERO_N; i += (size_t)gridDim.x * 1024)
        *reinterpret_cast<float4*>(ws + i) = make_float4(0.f, 0.f, 0.f, 0.f);
}

// ---------------------------------------------------------------------------
extern "C" void kernel_launch(void* const* d_in, const int* in_sizes, int n_in,
                              void* d_out, int out_size, void* d_ws, size_t ws_size,
                              hipStream_t stream) {
    const float* x_patched = (const float*)d_in[0];
    const float* mask      = (const float*)d_in[1];
    const float* Wx0       = (const float*)d_in[2];
    const float* Wxr       = (const float*)d_in[3];
    const float* Wh        = (const float*)d_in[4];
    const float* Wm        = (const float*)d_in[5];
    const float* Wo        = (const float*)d_in[6];
    const float* Wl        = (const float*)d_in[7];
    const float* Wout      = (const float*)d_in[8];
    float* out = (float*)d_out;
    float* ws  = (float*)d_ws;

    float* hs    = ws + OFF_HS;
    float* cs    = ws + OFF_CS;
    float* m_buf = ws + OFF_M;
    double* stats = (double*)(ws + OFF_STATS);
    float* xraw  = ws + OFF_XRAW;
    float* hraw  = ws + OFF_HRAW;
    float* mraw  = ws + OFF_MRAW;
    float* mem   = ws + OFF_MEM;
    float* opart = ws + OFF_OPART;
    float* oraw  = ws + OFF_ORAW;
    float* oxh   = ws + OFF_OXH;

    init_k<<<1024, 256, 0, stream>>>(ws);

    for (int t = 0; t < NSTEP; ++t) {
        for (int l = 0; l < NLAYER; ++l) {
            // ---- fused x/h/m gate convs
            const float* xin;
            int xin_bstride, mode, wx_ci;
            const float* wxp;
            if (l == 0) {
                if (t == 0) { xin = x_patched; xin_bstride = 20 * 16 * 1024; mode = 0; }
                else        { xin = x_patched; xin_bstride = 0;              mode = 1; }
                wxp = Wx0; wx_ci = 16;
            } else {
                xin = hs + (size_t)(l - 1) * 262144; xin_bstride = 65536; mode = 0;
                wxp = Wxr + (size_t)(l - 1) * 448 * 64 * 25; wx_ci = 64;
            }
            convcell_k<<<dim3(BB * 224), 256, 0, stream>>>(
                xin, xin_bstride, mode, t, x_patched, mask, out,
                wxp, wx_ci,
                hs + (size_t)l * 262144, Wh + (size_t)l * 256 * 64 * 25,
                m_buf, Wm + (size_t)l * 192 * 64 * 25,
                xraw, hraw, mraw, stats);
            // ---- gates: c_new, m_new, mem, oxh (+ zero stats slot 3)
            gates_k<<<256, 256, 0, stream>>>(
                xraw, hraw, mraw, stats,
                cs + (size_t)l * 262144, m_buf, mem, oxh);
            // ---- conv-o on mem (ci split into 4 chunks of 32)
            convo_k<<<dim3(256), 256, 0, stream>>>(
                mem, Wo + (size_t)l * 64 * 128 * 25, opart);
            // ---- sum partials + o stats
            statso_k<<<256, 256, 0, stream>>>(opart, oraw, stats);
            // ---- o gate, conv_last 1x1, h_new (+ zero stats slots 0-2)
            final_k<<<64, 256, 0, stream>>>(
                mem, oraw, oxh, stats,
                Wl + (size_t)l * 64 * 128, hs + (size_t)l * 262144);
        }
        out_k<<<16, 256, 0, stream>>>(hs + 3 * 262144, Wout, out, t);
    }
    (void)in_sizes; (void)n_in; (void)out_size; (void)ws_size;
}

// Round 3
// 13468.333 us; speedup vs baseline: 2.4319x; 2.4319x over previous
//
#include <hip/hip_runtime.h>
#include <cstddef>
#include <cstdint>

// ---------------------------------------------------------------------------
// PredRNN V1 (L=4, HID=64, 32x32, B=4, T=20 -> 19 steps).
// Round 3: 5x5 convs as implicit-GEMM on matrix cores (mfma_f32_16x16x32_f16)
// with fp16 hi/lo split (3 MFMAs) for ~fp32 accuracy. Swizzled LDS staging,
// weights pre-split to MFMA-native layout once per call.
// ---------------------------------------------------------------------------

#define BB 4
#define NLAYER 4
#define NSTEP 19

typedef _Float16 f16;
typedef _Float16 f16x8 __attribute__((ext_vector_type(8)));
typedef float f32x4 __attribute__((ext_vector_type(4)));

// workspace offsets (in floats)
constexpr size_t OFF_HS    = 0;              // [4][4][64][1024]
constexpr size_t OFF_CS    = 1048576;
constexpr size_t OFF_M     = 2097152;
constexpr size_t OFF_STATS = 2359296;        // 32 doubles
constexpr size_t OFF_XRAW  = 2359360;        // [4][448][1024]
constexpr size_t OFF_HRAW  = 4194368;        // [4][256][1024]
constexpr size_t OFF_MRAW  = 5242944;        // [4][192][1024]
constexpr size_t OFF_MEM   = 6029376;        // [4][128][1024]
constexpr size_t OFF_OPART = 6553664;        // [4][4][64][1024]
constexpr size_t OFF_ORAW  = 7602240;
constexpr size_t OFF_OXH   = 7864384;
constexpr size_t OFF_WF    = 8126528;        // f16 region: 12,390,400 f16
constexpr size_t ZERO_N    = OFF_XRAW;

// f16-element offsets inside WF
constexpr size_t WF_X0 = 0;                  // 25*2*448*32 = 716800
constexpr size_t WF_XR = 716800;             // + lr*1433600 (lr=0..2)
constexpr size_t WF_H  = 5017600;            // + l*819200
constexpr size_t WF_M  = 8294400;            // + l*614400
constexpr size_t WF_O  = 10752000;           // + l*409600  (end 12390400)

__device__ __forceinline__ float sigmoidf_(float x) {
    return 1.0f / (1.0f + __expf(-x));
}

__device__ __forceinline__ float fast_tanh(float x) {
    float ax = fabsf(x);
    float e = __expf(2.0f * ax);
    float r = 1.0f - 2.0f / (e + 1.0f);
    return copysignf(r, x);
}

__device__ __forceinline__ void ln_params(const double* stats, int slot, int b,
                                          float N, float& mu, float& rs) {
    double s1 = stats[slot * 8 + b * 2 + 0];
    double s2 = stats[slot * 8 + b * 2 + 1];
    double mud = s1 / (double)N;
    double var = s2 / (double)N - mud * mud;
    mu = (float)mud;
    float v = (float)var + 1e-5f;
    float r = rsqrtf(v);
    r = r * (1.5f - 0.5f * v * r * r);
    rs = r;
}

// ----------------------- weight prep: fp32 -> f16 hi/lo --------------------
// src: w[co][ci_src][5][5]  ->  dst: [tap(25)][split(2)][co][ci_pad]
__global__ __launch_bounds__(256)
void prep_k(const float* __restrict__ src, f16* __restrict__ dst,
            int CO, int CIs, int CIp) {
    int idx = blockIdx.x * 256 + threadIdx.x;
    int total = CO * CIp * 25;
    if (idx >= total) return;
    int ci = idx % CIp;
    int rem = idx / CIp;
    int co = rem % CO;
    int tap = rem / CO;
    float v = (ci < CIs) ? src[((size_t)co * CIs + ci) * 25 + tap] : 0.f;
    f16 hi = (f16)v;
    f16 lo = (f16)(v - (float)hi);
    dst[((size_t)(tap * 2 + 0) * CO + co) * CIp + ci] = hi;
    dst[((size_t)(tap * 2 + 1) * CO + co) * CIp + ci] = lo;
}

// --------- fused x/h/m gate convs as implicit GEMM on matrix cores ---------
// grid: b(4) x [x:7x16 | h:4x16 | m:3x16] = 896 blocks. Block = 64co x 64px
// (2 image rows). Wave(4) = 32co x 32px. Input staged per 32-ci chunk into
// LDS as f16 hi/lo, layout: pixel-major, 4 ci-groups of 8 per pixel, slot
// XOR-swizzled for conflict-free ds_read_b128.
__global__ __launch_bounds__(256)
void mfconv_k(const float* __restrict__ xsrc, int xbstride, int xCI, int xCIpad,
              const f16* __restrict__ wfx,
              const float* __restrict__ hsrc, const f16* __restrict__ wfh,
              const float* __restrict__ msrc, const f16* __restrict__ wfm,
              const float* __restrict__ x_patched, const float* __restrict__ mask,
              const float* __restrict__ prevout, int t, int domix,
              float* __restrict__ xraw, float* __restrict__ hraw,
              float* __restrict__ mraw, double* __restrict__ stats) {
    __shared__ alignas(16) f16 lds[14208];   // [2 splits][222 px][32 ci-slots]
    const int tid = threadIdx.x;
    int bid = blockIdx.x;
    const int b = bid / 224;
    int g = bid % 224;
    int path, cog, pxg, CO, CI, CIpad;
    const f16* wf;
    const float* in;
    float* outp;
    if (g < 112) {
        path = 0; cog = g >> 4; pxg = g & 15;
        CO = 448; CI = xCI; CIpad = xCIpad; wf = wfx; outp = xraw;
        in = xsrc + (size_t)b * xbstride;
    } else if (g < 176) {
        g -= 112; path = 1; cog = g >> 4; pxg = g & 15;
        CO = 256; CI = 64; CIpad = 64; wf = wfh; outp = hraw;
        in = hsrc + (size_t)b * 65536;
    } else {
        g -= 176; path = 2; cog = g >> 4; pxg = g & 15;
        CO = 192; CI = 64; CIpad = 64; wf = wfm; outp = mraw;
        in = msrc + (size_t)b * 65536;
    }
    const int y0 = pxg * 2;
    const bool mix = (path == 0) && (domix != 0);

    // staging thread ids: (ci_local 0..31, staged row 0..7; rows 6,7 idle)
    const int ci_l = tid & 31, sr = tid >> 5;
    const int skg = ci_l >> 3, scb = ci_l & 7;
    const int sy = y0 - 2 + sr;
    const bool rowok = (sr < 6) && ((unsigned)sy < 32u);

    // compute ids
    const int w = tid >> 6, lane = tid & 63;
    const int coh = w & 1, wr = w >> 1;
    const int n = lane & 15, kq = lane >> 4;
    const size_t wtap = (size_t)2 * CO * CIpad;   // f16 elems per tap
    const size_t laneA = (size_t)(cog * 64 + coh * 32 + n) * CIpad + kq * 8;
    const int pbase = (wr + 2) * 37 + 2 + n;

    f32x4 acc[2][2] = {};

    const int nchunks = CIpad >> 5;
    for (int chunk = 0; chunk < nchunks; ++chunk) {
        __syncthreads();
        // ---- stage 32 channels, rows y0-2..y0+3, cols -2..33 ----
        {
            const int cig = chunk * 32 + ci_l;
            float v[32];
            #pragma unroll
            for (int k = 0; k < 32; ++k) v[k] = 0.f;
            if (rowok && cig < CI) {
                if (mix) {
                    const float* xfr = x_patched + ((size_t)b * 20 + t) * 16384
                                       + (size_t)cig * 1024 + sy * 32;
                    const float* xor_ = prevout
                                       + (((size_t)b * NSTEP + (t - 1)) * 16 + cig) * 1024
                                       + sy * 32;
                    const float* mkr = mask + ((size_t)b * 18 + (t - 1)) * 1024 + sy * 32;
                    #pragma unroll
                    for (int k = 0; k < 8; ++k) {
                        float4 a = *(const float4*)(xfr + k * 4);
                        float4 o = *(const float4*)(xor_ + k * 4);
                        float4 mm = *(const float4*)(mkr + k * 4);
                        v[4 * k + 0] = mm.x * a.x + (1.f - mm.x) * o.x;
                        v[4 * k + 1] = mm.y * a.y + (1.f - mm.y) * o.y;
                        v[4 * k + 2] = mm.z * a.z + (1.f - mm.z) * o.z;
                        v[4 * k + 3] = mm.w * a.w + (1.f - mm.w) * o.w;
                    }
                } else {
                    const float* rp = in + (size_t)cig * 1024 + sy * 32;
                    #pragma unroll
                    for (int k = 0; k < 8; ++k) {
                        float4 q = *(const float4*)(rp + k * 4);
                        v[4 * k + 0] = q.x; v[4 * k + 1] = q.y;
                        v[4 * k + 2] = q.z; v[4 * k + 3] = q.w;
                    }
                }
            }
            if (sr < 6) {
                #define STW(c, val) { int p = sr * 37 + (c);                         \
                    int s_ = skg ^ ((p >> 1) & 3);                                   \
                    int off = p * 32 + (s_ << 3) + scb;                              \
                    f16 hi = (f16)(val); f16 lo = (f16)((val) - (float)hi);          \
                    lds[off] = hi; lds[7104 + off] = lo; }
                STW(0, 0.f); STW(1, 0.f);
                #pragma unroll
                for (int x = 0; x < 32; ++x) STW(x + 2, v[x]);
                STW(34, 0.f); STW(35, 0.f);
                #undef STW
            }
        }
        __syncthreads();
        // ---- 25 taps over staged chunk ----
        const f16* wfc = wf + chunk * 32;
        for (int ky = 0; ky < 5; ++ky) {
            const f16* wfk = wfc + (size_t)(ky * 5) * wtap;
            const int pky = pbase + (ky - 2) * 37;
            #pragma unroll
            for (int kx = 0; kx < 5; ++kx) {
                const f16* wA = wfk + (size_t)kx * wtap;
                const f16* wAl = wA + (size_t)CO * CIpad;
                f16x8 a0h = *(const f16x8*)(wA + laneA);
                f16x8 a1h = *(const f16x8*)(wA + laneA + (size_t)16 * CIpad);
                f16x8 a0l = *(const f16x8*)(wAl + laneA);
                f16x8 a1l = *(const f16x8*)(wAl + laneA + (size_t)16 * CIpad);
                #pragma unroll
                for (int pt = 0; pt < 2; ++pt) {
                    int p = pky + (kx - 2) + pt * 16;
                    int off = p * 32 + ((kq ^ ((p >> 1) & 3)) << 3);
                    f16x8 bh = *(const f16x8*)&lds[off];
                    f16x8 bl = *(const f16x8*)&lds[7104 + off];
                    acc[0][pt] = __builtin_amdgcn_mfma_f32_16x16x32_f16(a0h, bh, acc[0][pt], 0, 0, 0);
                    acc[1][pt] = __builtin_amdgcn_mfma_f32_16x16x32_f16(a1h, bh, acc[1][pt], 0, 0, 0);
                    acc[0][pt] = __builtin_amdgcn_mfma_f32_16x16x32_f16(a0l, bh, acc[0][pt], 0, 0, 0);
                    acc[1][pt] = __builtin_amdgcn_mfma_f32_16x16x32_f16(a1l, bh, acc[1][pt], 0, 0, 0);
                    acc[0][pt] = __builtin_amdgcn_mfma_f32_16x16x32_f16(a0h, bl, acc[0][pt], 0, 0, 0);
                    acc[1][pt] = __builtin_amdgcn_mfma_f32_16x16x32_f16(a1h, bl, acc[1][pt], 0, 0, 0);
                }
            }
        }
    }

    // ---- store raw conv outputs + LN stats ----
    float* ob = outp + ((size_t)b * CO + cog * 64 + coh * 32) * 1024 + (y0 + wr) * 32;
    double s1 = 0.0, s2 = 0.0;
    #pragma unroll
    for (int ct = 0; ct < 2; ++ct)
        #pragma unroll
        for (int pt = 0; pt < 2; ++pt)
            #pragma unroll
            for (int j = 0; j < 4; ++j) {
                float vv = acc[ct][pt][j];
                ob[(size_t)(ct * 16 + kq * 4 + j) * 1024 + pt * 16 + n] = vv;
                s1 += vv; s2 += (double)vv * vv;
            }
    __syncthreads();
    double* red = (double*)lds;
    red[tid] = s1; red[256 + tid] = s2;
    __syncthreads();
    for (int s = 128; s > 0; s >>= 1) {
        if (tid < s) { red[tid] += red[tid + s]; red[256 + tid] += red[256 + tid + s]; }
        __syncthreads();
    }
    if (tid == 0) {
        atomicAdd(&stats[path * 8 + b * 2 + 0], red[0]);
        atomicAdd(&stats[path * 8 + b * 2 + 1], red[256]);
    }
}

// ----------------- conv-o (mem 128ci -> 64co) on matrix cores --------------
// grid: b(4) x pxg(16) x chunk(4) = 256 blocks; partial outputs per chunk.
__global__ __launch_bounds__(256)
void convo_mf_k(const float* __restrict__ mem, const f16* __restrict__ wfo,
                float* __restrict__ opart) {
    __shared__ alignas(16) f16 lds[14208];
    const int tid = threadIdx.x;
    const int bid = blockIdx.x;
    const int chunk = bid & 3;
    const int pxg = (bid >> 2) & 15;
    const int b = bid >> 6;
    const int y0 = pxg * 2;
    const float* in = mem + (size_t)b * 131072;

    const int ci_l = tid & 31, sr = tid >> 5;
    const int skg = ci_l >> 3, scb = ci_l & 7;
    const int sy = y0 - 2 + sr;
    const bool rowok = (sr < 6) && ((unsigned)sy < 32u);

    const int w = tid >> 6, lane = tid & 63;
    const int coh = w & 1, wr = w >> 1;
    const int n = lane & 15, kq = lane >> 4;
    const size_t wtap = (size_t)2 * 64 * 128;
    const size_t laneA = (size_t)(coh * 32 + n) * 128 + chunk * 32 + kq * 8;
    const int pbase = (wr + 2) * 37 + 2 + n;

    f32x4 acc[2][2] = {};

    {
        const int cig = chunk * 32 + ci_l;
        float v[32];
        #pragma unroll
        for (int k = 0; k < 32; ++k) v[k] = 0.f;
        if (rowok) {
            const float* rp = in + (size_t)cig * 1024 + sy * 32;
            #pragma unroll
            for (int k = 0; k < 8; ++k) {
                float4 q = *(const float4*)(rp + k * 4);
                v[4 * k + 0] = q.x; v[4 * k + 1] = q.y;
                v[4 * k + 2] = q.z; v[4 * k + 3] = q.w;
            }
        }
        if (sr < 6) {
            #define STW(c, val) { int p = sr * 37 + (c);                         \
                int s_ = skg ^ ((p >> 1) & 3);                                   \
                int off = p * 32 + (s_ << 3) + scb;                              \
                f16 hi = (f16)(val); f16 lo = (f16)((val) - (float)hi);          \
                lds[off] = hi; lds[7104 + off] = lo; }
            STW(0, 0.f); STW(1, 0.f);
            #pragma unroll
            for (int x = 0; x < 32; ++x) STW(x + 2, v[x]);
            STW(34, 0.f); STW(35, 0.f);
            #undef STW
        }
    }
    __syncthreads();
    for (int ky = 0; ky < 5; ++ky) {
        const f16* wfk = wfo + (size_t)(ky * 5) * wtap;
        const int pky = pbase + (ky - 2) * 37;
        #pragma unroll
        for (int kx = 0; kx < 5; ++kx) {
            const f16* wA = wfk + (size_t)kx * wtap;
            const f16* wAl = wA + (size_t)64 * 128;
            f16x8 a0h = *(const f16x8*)(wA + laneA);
            f16x8 a1h = *(const f16x8*)(wA + laneA + (size_t)16 * 128);
            f16x8 a0l = *(const f16x8*)(wAl + laneA);
            f16x8 a1l = *(const f16x8*)(wAl + laneA + (size_t)16 * 128);
            #pragma unroll
            for (int pt = 0; pt < 2; ++pt) {
                int p = pky + (kx - 2) + pt * 16;
                int off = p * 32 + ((kq ^ ((p >> 1) & 3)) << 3);
                f16x8 bh = *(const f16x8*)&lds[off];
                f16x8 bl = *(const f16x8*)&lds[7104 + off];
                acc[0][pt] = __builtin_amdgcn_mfma_f32_16x16x32_f16(a0h, bh, acc[0][pt], 0, 0, 0);
                acc[1][pt] = __builtin_amdgcn_mfma_f32_16x16x32_f16(a1h, bh, acc[1][pt], 0, 0, 0);
                acc[0][pt] = __builtin_amdgcn_mfma_f32_16x16x32_f16(a0l, bh, acc[0][pt], 0, 0, 0);
                acc[1][pt] = __builtin_amdgcn_mfma_f32_16x16x32_f16(a1l, bh, acc[1][pt], 0, 0, 0);
                acc[0][pt] = __builtin_amdgcn_mfma_f32_16x16x32_f16(a0h, bl, acc[0][pt], 0, 0, 0);
                acc[1][pt] = __builtin_amdgcn_mfma_f32_16x16x32_f16(a1h, bl, acc[1][pt], 0, 0, 0);
            }
        }
    }
    float* ob = opart + (size_t)chunk * 262144
              + ((size_t)b * 64 + coh * 32) * 1024 + (y0 + wr) * 32;
    #pragma unroll
    for (int ct = 0; ct < 2; ++ct)
        #pragma unroll
        for (int pt = 0; pt < 2; ++pt)
            #pragma unroll
            for (int j = 0; j < 4; ++j)
                ob[(size_t)(ct * 16 + kq * 4 + j) * 1024 + pt * 16 + n] = acc[ct][pt][j];
}

// ------------------------------- gates -------------------------------------
#define LD4(dst, p) { float4 _v = *reinterpret_cast<const float4*>(p); \
                      (dst)[0]=_v.x; (dst)[1]=_v.y; (dst)[2]=_v.z; (dst)[3]=_v.w; }
#define ST4(p, src) { *reinterpret_cast<float4*>(p) = \
                      make_float4((src)[0], (src)[1], (src)[2], (src)[3]); }

__global__ __launch_bounds__(256)
void gates_k(const float* __restrict__ xraw, const float* __restrict__ hraw,
             const float* __restrict__ mraw, double* __restrict__ stats,
             float* __restrict__ cs_l, float* __restrict__ m_buf,
             float* __restrict__ mem, float* __restrict__ oxh) {
    int e4 = blockIdx.x * 256 + threadIdx.x;
    if (e4 < 8) stats[24 + e4] = 0.0;
    int b = e4 >> 14;
    int r = (e4 & 16383) << 2;

    float mu_x, rs_x, mu_h, rs_h, mu_m, rs_m;
    ln_params(stats, 0, b, 458752.f, mu_x, rs_x);
    ln_params(stats, 1, b, 262144.f, mu_h, rs_h);
    ln_params(stats, 2, b, 196608.f, mu_m, rs_m);

    const float* xb = xraw + (size_t)b * 458752 + r;
    const float* hb = hraw + (size_t)b * 262144 + r;
    const float* mb = mraw + (size_t)b * 196608 + r;
    float* csb  = cs_l  + (size_t)b * 65536 + r;
    float* mbb  = m_buf + (size_t)b * 65536 + r;
    float* memc = mem   + (size_t)b * 131072 + r;
    float* memm = memc + 65536;
    float* oxb  = oxh   + (size_t)b * 65536 + r;

    float X[7][4], H[4][4], M[3][4], C[4], MM[4];
    #pragma unroll
    for (int k = 0; k < 7; ++k) LD4(X[k], xb + k * 65536);
    #pragma unroll
    for (int k = 0; k < 4; ++k) LD4(H[k], hb + k * 65536);
    #pragma unroll
    for (int k = 0; k < 3; ++k) LD4(M[k], mb + k * 65536);
    LD4(C, csb);
    LD4(MM, mbb);

    float cn[4], mn[4], ox4[4];
    #pragma unroll
    for (int j = 0; j < 4; ++j) {
        float ix  = (X[0][j] - mu_x) * rs_x;
        float fx  = (X[1][j] - mu_x) * rs_x;
        float gx  = (X[2][j] - mu_x) * rs_x;
        float ixp = (X[3][j] - mu_x) * rs_x;
        float fxp = (X[4][j] - mu_x) * rs_x;
        float gxp = (X[5][j] - mu_x) * rs_x;
        float ox  = (X[6][j] - mu_x) * rs_x;
        float ih  = (H[0][j] - mu_h) * rs_h;
        float fh  = (H[1][j] - mu_h) * rs_h;
        float gh  = (H[2][j] - mu_h) * rs_h;
        float oh  = (H[3][j] - mu_h) * rs_h;
        float im  = (M[0][j] - mu_m) * rs_m;
        float fm  = (M[1][j] - mu_m) * rs_m;
        float gm  = (M[2][j] - mu_m) * rs_m;

        float i  = sigmoidf_(ix + ih);
        float f  = sigmoidf_(fx + fh + 1.0f);
        float gg = fast_tanh(gx + gh);
        float c  = f * C[j] + i * gg;
        float ip = sigmoidf_(ixp + im);
        float fp = sigmoidf_(fxp + fm + 1.0f);
        float gp = fast_tanh(gxp + gm);
        float m2 = fp * MM[j] + ip * gp;
        cn[j] = c; mn[j] = m2; ox4[j] = ox + oh;
    }
    ST4(csb, cn); ST4(mbb, mn); ST4(memc, cn); ST4(memm, mn); ST4(oxb, ox4);
}

// ------------------ sum conv-o partials + stats -----------------------------
__global__ __launch_bounds__(256)
void statso_k(const float* __restrict__ opart, float* __restrict__ oraw,
              double* __restrict__ stats) {
    __shared__ double red[512];
    int e4 = blockIdx.x * 256 + threadIdx.x;
    int b = e4 >> 14;
    int r = e4 << 2;
    float4 v0 = *reinterpret_cast<const float4*>(opart + r);
    float4 v1 = *reinterpret_cast<const float4*>(opart + 262144 + r);
    float4 v2 = *reinterpret_cast<const float4*>(opart + 524288 + r);
    float4 v3 = *reinterpret_cast<const float4*>(opart + 786432 + r);
    float4 s;
    s.x = v0.x + v1.x + v2.x + v3.x;
    s.y = v0.y + v1.y + v2.y + v3.y;
    s.z = v0.z + v1.z + v2.z + v3.z;
    s.w = v0.w + v1.w + v2.w + v3.w;
    *reinterpret_cast<float4*>(oraw + r) = s;
    double s1 = (double)s.x + (double)s.y + (double)s.z + (double)s.w;
    double s2 = (double)s.x * s.x + (double)s.y * s.y +
                (double)s.z * s.z + (double)s.w * s.w;
    int t = threadIdx.x;
    red[t] = s1; red[256 + t] = s2;
    __syncthreads();
    for (int st = 128; st > 0; st >>= 1) {
        if (t < st) { red[t] += red[t + st]; red[256 + t] += red[256 + t + st]; }
        __syncthreads();
    }
    if (t == 0) {
        atomicAdd(&stats[24 + b * 2 + 0], red[0]);
        atomicAdd(&stats[24 + b * 2 + 1], red[256]);
    }
}

// --------------- o-gate + 1x1 conv_last + h_new -----------------------------
__global__ __launch_bounds__(256)
void final_k(const float* __restrict__ mem, const float* __restrict__ oraw,
             const float* __restrict__ oxh, double* __restrict__ stats,
             const float* __restrict__ Wl_l, float* __restrict__ hs_l) {
    int bi = blockIdx.x;
    int b = bi >> 4, pxq = (bi >> 2) & 3, coq = bi & 3;
    int px = pxq * 256 + threadIdx.x;
    const float* memb = mem + (size_t)b * 131072 + px;
    float acc[16];
    #pragma unroll
    for (int k = 0; k < 16; ++k) acc[k] = 0.f;
    for (int ci = 0; ci < 128; ++ci) {
        float v = memb[ci * 1024];
        #pragma unroll
        for (int k = 0; k < 16; ++k)
            acc[k] = fmaf(v, Wl_l[(coq * 16 + k) * 128 + ci], acc[k]);
    }
    float mu, rs;
    ln_params(stats, 3, b, 65536.f, mu, rs);
    #pragma unroll
    for (int k = 0; k < 16; ++k) {
        int co = coq * 16 + k;
        size_t idx = ((size_t)b * 64 + co) * 1024 + px;
        float o = sigmoidf_(oxh[idx] + (oraw[idx] - mu) * rs);
        hs_l[idx] = o * fast_tanh(acc[k]);
    }
    if (bi == 0 && threadIdx.x < 24) stats[threadIdx.x] = 0.0;
}

// --------------------- 1x1 output conv (64 -> 16) ---------------------------
__global__ __launch_bounds__(256)
void out_k(const float* __restrict__ h3, const float* __restrict__ Wout,
           float* __restrict__ out, int t) {
    int e = blockIdx.x * 256 + threadIdx.x;
    int b = e >> 10, px = e & 1023;
    const float* hb = h3 + (size_t)b * 65536 + px;
    float acc[16];
    #pragma unroll
    for (int k = 0; k < 16; ++k) acc[k] = 0.f;
    for (int ci = 0; ci < 64; ++ci) {
        float v = hb[ci * 1024];
        #pragma unroll
        for (int k = 0; k < 16; ++k) acc[k] = fmaf(v, Wout[k * 64 + ci], acc[k]);
    }
    #pragma unroll
    for (int k = 0; k < 16; ++k)
        out[(((size_t)b * NSTEP + t) * 16 + k) * 1024 + px] = acc[k];
}

// ------------------------------ init (zero state) ---------------------------
__global__ __launch_bounds__(256)
void init_k(float* __restrict__ ws) {
    size_t i = ((size_t)blockIdx.x * 256 + threadIdx.x) * 4;
    for (; i < ZERO_N; i += (size_t)gridDim.x * 1024)
        *reinterpret_cast<float4*>(ws + i) = make_float4(0.f, 0.f, 0.f, 0.f);
}

// ---------------------------------------------------------------------------
extern "C" void kernel_launch(void* const* d_in, const int* in_sizes, int n_in,
                              void* d_out, int out_size, void* d_ws, size_t ws_size,
                              hipStream_t stream) {
    const float* x_patched = (const float*)d_in[0];
    const float* mask      = (const float*)d_in[1];
    const float* Wx0       = (const float*)d_in[2];
    const float* Wxr       = (const float*)d_in[3];
    const float* Wh        = (const float*)d_in[4];
    const float* Wm        = (const float*)d_in[5];
    const float* Wo        = (const float*)d_in[6];
    const float* Wl        = (const float*)d_in[7];
    const float* Wout      = (const float*)d_in[8];
    float* out = (float*)d_out;
    float* ws  = (float*)d_ws;

    float* hs    = ws + OFF_HS;
    float* cs    = ws + OFF_CS;
    float* m_buf = ws + OFF_M;
    double* stats = (double*)(ws + OFF_STATS);
    float* xraw  = ws + OFF_XRAW;
    float* hraw  = ws + OFF_HRAW;
    float* mraw  = ws + OFF_MRAW;
    float* mem   = ws + OFF_MEM;
    float* opart = ws + OFF_OPART;
    float* oraw  = ws + OFF_ORAW;
    float* oxh   = ws + OFF_OXH;
    f16*   wfb   = (f16*)(ws + OFF_WF);

    init_k<<<1024, 256, 0, stream>>>(ws);

    // ---- weight prep (every call; ~24MB once) ----
    prep_k<<<(448 * 32 * 25 + 255) / 256, 256, 0, stream>>>(
        Wx0, wfb + WF_X0, 448, 16, 32);
    for (int lr = 0; lr < 3; ++lr)
        prep_k<<<(448 * 64 * 25 + 255) / 256, 256, 0, stream>>>(
            Wxr + (size_t)lr * 448 * 64 * 25, wfb + WF_XR + (size_t)lr * 1433600,
            448, 64, 64);
    for (int l = 0; l < 4; ++l)
        prep_k<<<(256 * 64 * 25 + 255) / 256, 256, 0, stream>>>(
            Wh + (size_t)l * 256 * 64 * 25, wfb + WF_H + (size_t)l * 819200,
            256, 64, 64);
    for (int l = 0; l < 4; ++l)
        prep_k<<<(192 * 64 * 25 + 255) / 256, 256, 0, stream>>>(
            Wm + (size_t)l * 192 * 64 * 25, wfb + WF_M + (size_t)l * 614400,
            192, 64, 64);
    for (int l = 0; l < 4; ++l)
        prep_k<<<(64 * 128 * 25 + 255) / 256, 256, 0, stream>>>(
            Wo + (size_t)l * 64 * 128 * 25, wfb + WF_O + (size_t)l * 409600,
            64, 128, 128);

    for (int t = 0; t < NSTEP; ++t) {
        for (int l = 0; l < NLAYER; ++l) {
            const float* xsrc;
            int xbstride, domix, xCI, xCIpad;
            const f16* wfx;
            if (l == 0) {
                xsrc = x_patched; xCI = 16; xCIpad = 32; wfx = wfb + WF_X0;
                if (t == 0) { xbstride = 327680; domix = 0; }
                else        { xbstride = 0;      domix = 1; }
            } else {
                xsrc = hs + (size_t)(l - 1) * 262144;
                xbstride = 65536; domix = 0; xCI = 64; xCIpad = 64;
                wfx = wfb + WF_XR + (size_t)(l - 1) * 1433600;
            }
            mfconv_k<<<dim3(BB * 224), 256, 0, stream>>>(
                xsrc, xbstride, xCI, xCIpad, wfx,
                hs + (size_t)l * 262144, wfb + WF_H + (size_t)l * 819200,
                m_buf, wfb + WF_M + (size_t)l * 614400,
                x_patched, mask, out, t, domix,
                xraw, hraw, mraw, stats);
            gates_k<<<256, 256, 0, stream>>>(
                xraw, hraw, mraw, stats,
                cs + (size_t)l * 262144, m_buf, mem, oxh);
            convo_mf_k<<<dim3(256), 256, 0, stream>>>(
                mem, wfb + WF_O + (size_t)l * 409600, opart);
            statso_k<<<256, 256, 0, stream>>>(opart, oraw, stats);
            final_k<<<64, 256, 0, stream>>>(
                mem, oraw, oxh, stats,
                Wl + (size_t)l * 64 * 128, hs + (size_t)l * 262144);
        }
        out_k<<<16, 256, 0, stream>>>(hs + 3 * 262144, Wout, out, t);
    }
    (void)in_sizes; (void)n_in; (void)out_size; (void)ws_size;
}